// Round 11
// baseline (190.229 us; speedup 1.0000x reference)
//
#include <hip/hip_runtime.h>
#include <hip/hip_bf16.h>

// ---------------------------------------------------------------------------
// CrossFormerBlock on MI355X (gfx950)
// B=1 D=16 H=32 W=32 T=4 C=128, G=4, NH=8, HD=16, NW=256 windows, N=256 tok/win
// R11: conv scheduling fix — __launch_bounds__(256,1) (ILP scheduling, VGPR
// budget 512) + memory-clobber fence pinning all 27 tap loads before the FMA
// block (R10 showed the scheduler re-sinks loads without it; VGPR stayed 32).
// Rest unchanged from R10.
// ---------------------------------------------------------------------------

typedef __attribute__((ext_vector_type(8))) short  s16x8;
typedef __attribute__((ext_vector_type(4))) short  s16x4;
typedef __attribute__((ext_vector_type(4))) float  f32x4;
typedef __attribute__((ext_vector_type(8))) _Float16 f16x8;
typedef __attribute__((ext_vector_type(4))) _Float16 f16x4;

#define CC    128
#define NWIN  256
#define TOKS  65536            // total tokens = D*H*W*T
#define SCALE 0.25f
#define LNEPS 1e-5f
// padded spatial geometry for conv
#define PD 18
#define PH 34
#define PW 34
#define PSITES (PD*PH*PW)                // 20808
#define Y1P_SHORTS ((size_t)PSITES*512)  // *4t*128c

__device__ __forceinline__ float b2f(short s) {
  union { unsigned u; float f; } c; c.u = ((unsigned)(unsigned short)s) << 16; return c.f;
}
__device__ __forceinline__ short f2b(float f) {
  __hip_bfloat16 h = __float2bfloat16(f);
  return *reinterpret_cast<short*>(&h);
}
__device__ __forceinline__ float fast_gelu(float x) {
  float u = 1.595769122f * x * fmaf(0.044715f, x*x, 1.0f);
  return x / (1.0f + __expf(-u));
}

__device__ __forceinline__ f32x4 mfma16x16x16_bf16(s16x4 a, s16x4 b, f32x4 c) {
#if __has_builtin(__builtin_amdgcn_mfma_f32_16x16x16_bf16)
  return __builtin_amdgcn_mfma_f32_16x16x16_bf16(a, b, c, 0, 0, 0);
#elif __has_builtin(__builtin_amdgcn_mfma_f32_16x16x16bf16_1k)
  return __builtin_amdgcn_mfma_f32_16x16x16bf16_1k(a, b, c, 0, 0, 0);
#else
  f32x4 d;
  asm("v_mfma_f32_16x16x16_bf16 %0, %1, %2, %3" : "=v"(d) : "v"(a), "v"(b), "v"(c));
  return d;
#endif
}

// ---------------------------------------------------------------------------
// Kernel 0: weight prep
// ---------------------------------------------------------------------------
__global__ void prep_kernel(const float* __restrict__ qkv_w, const float* __restrict__ proj_w,
                            const float* __restrict__ fc1_w, const float* __restrict__ fc2_w,
                            const float* __restrict__ conv_w,
                            __hip_bfloat16* wq, __hip_bfloat16* wp,
                            __hip_bfloat16* w1, __hip_bfloat16* w2, float* cwT) {
  int idx = blockIdx.x * 256 + threadIdx.x;
  if (idx < 49152) {
    wq[idx] = __float2bfloat16(qkv_w[idx]);
  } else if (idx < 65536) {
    wp[idx - 49152] = __float2bfloat16(proj_w[idx - 49152]);
  } else if (idx < 131072) {
    w1[idx - 65536] = __float2bfloat16(fc1_w[idx - 65536]);
  } else if (idx < 196608) {
    w2[idx - 131072] = __float2bfloat16(fc2_w[idx - 131072]);
  } else if (idx < 196608 + 27*128) {
    int j = idx - 196608;
    int tap = j >> 7, c = j & 127;
    cwT[tap*128 + c] = conv_w[c*27 + tap];   // (C,1,3,3,3) -> (27,C)
  }
}

// ---------------------------------------------------------------------------
// Kernel: zero only the BORDER sites of the padded y1 buffer (4424 sites).
// ---------------------------------------------------------------------------
__global__ __launch_bounds__(256) void border_zero_kernel(short* __restrict__ y1p) {
  int idx = blockIdx.x*256 + threadIdx.x;
  if (idx >= PSITES*64) return;
  int site = idx >> 6;
  int w = site % PW, hh = (site / PW) % PH, d = site / (PW*PH);
  if (d != 0 && d != PD-1 && hh != 0 && hh != PH-1 && w != 0 && w != PW-1) return;
  *(s16x8*)&y1p[(size_t)site*512 + (idx & 63)*8] = (s16x8)0;
}

// ---------------------------------------------------------------------------
// Kernel 1: LN1 + positional/temporal embed -> window-token layout bf16
// ---------------------------------------------------------------------------
__global__ __launch_bounds__(256) void ln1_pe_kernel(
    const float* __restrict__ x, const float* __restrict__ g, const float* __restrict__ b,
    const float* __restrict__ pos, const float* __restrict__ te,
    __hip_bfloat16* __restrict__ hb) {
  int wv = threadIdx.x >> 6, lane = threadIdx.x & 63;
  int tk = blockIdx.x * 4 + wv;                 // tk = wid*256 + n
  int wid = tk >> 8, n = tk & 255;
  int t = n >> 6, gd = (n >> 4) & 3, gh = (n >> 2) & 3, gw = n & 3;
  int wd = wid >> 6, wh = (wid >> 3) & 7, ww = wid & 7;
  int d = wd*4 + gd, h = wh*4 + gh, w = ww*4 + gw;
  size_t xoff = ((size_t)((d*32 + h)*32 + w)*4 + t) * CC;
  float v0 = x[xoff + lane], v1 = x[xoff + lane + 64];
  float s = v0 + v1, sq = v0*v0 + v1*v1;
  for (int m = 32; m; m >>= 1) { s += __shfl_xor(s, m); sq += __shfl_xor(sq, m); }
  float mean = s * (1.f/128.f);
  float var  = sq * (1.f/128.f) - mean*mean;
  float rstd = rsqrtf(var + LNEPS);
  int pb = ((gd*4 + gh)*4 + gw) * CC, tb = t * CC;
  float h0 = (v0 - mean)*rstd*g[lane]    + b[lane]    + pos[pb + lane]    + te[tb + lane];
  float h1 = (v1 - mean)*rstd*g[lane+64] + b[lane+64] + pos[pb + lane+64] + te[tb + lane+64];
  hb[(size_t)tk*CC + lane]      = __float2bfloat16(h0);
  hb[(size_t)tk*CC + lane + 64] = __float2bfloat16(h1);
}

// ---------------------------------------------------------------------------
// GEMM template: 128x128 tile, BK=64, 4 waves, compile-time K (KK).
// acc[i][j] = mfma(b[j], a[i], acc) -> D^T fragments (vector stores).
// ---------------------------------------------------------------------------
template <int MODE, int KK>
__global__ __launch_bounds__(256) void gemm_kernel(
    const short* __restrict__ Ag, const short* __restrict__ Wg,
    const float* __restrict__ bias,
    void* __restrict__ out0, const _Float16* __restrict__ resid) {
  __shared__ __align__(16) short As[128*72];
  __shared__ __align__(16) short Bs[128*72];
  const int tid = threadIdx.x;
  const int m0 = blockIdx.x * 128;
  const int n0 = blockIdx.y * 128;
  const int lane = tid & 63, wv = tid >> 6;
  const int wr = wv >> 1, wc = wv & 1;
  const int fr = lane & 15, kg = lane >> 4;

  f32x4 acc[4][4];
#pragma unroll
  for (int i = 0; i < 4; ++i)
#pragma unroll
    for (int j = 0; j < 4; ++j) acc[i][j] = (f32x4)0.f;

#pragma unroll
  for (int kc = 0; kc < KK; kc += 64) {
    __syncthreads();
#pragma unroll
    for (int i = 0; i < 4; ++i) {
      int c = tid + i*256;
      int row = c >> 3, col8 = (c & 7) * 8;
      s16x8 va = *(const s16x8*)(Ag + (size_t)(m0 + row)*KK + kc + col8);
      s16x8 vb = *(const s16x8*)(Wg + (size_t)(n0 + row)*KK + kc + col8);
      *(s16x8*)&As[row*72 + col8] = va;
      *(s16x8*)&Bs[row*72 + col8] = vb;
    }
    __syncthreads();
#pragma unroll
    for (int ks = 0; ks < 2; ++ks) {
      s16x8 a[4], b[4];
#pragma unroll
      for (int i = 0; i < 4; ++i)
        a[i] = *(const s16x8*)&As[(wr*64 + i*16 + fr)*72 + ks*32 + kg*8];
#pragma unroll
      for (int j = 0; j < 4; ++j)
        b[j] = *(const s16x8*)&Bs[(wc*64 + j*16 + fr)*72 + ks*32 + kg*8];
#pragma unroll
      for (int i = 0; i < 4; ++i)
#pragma unroll
        for (int j = 0; j < 4; ++j)
          acc[i][j] = __builtin_amdgcn_mfma_f32_16x16x32_bf16(b[j], a[i], acc[i][j], 0, 0, 0);
    }
  }

  const int nbb = n0 + wc*64 + kg*4;
  f32x4 bj4[4];
#pragma unroll
  for (int j = 0; j < 4; ++j) bj4[j] = *(const f32x4*)&bias[nbb + j*16];

#pragma unroll
  for (int i = 0; i < 4; ++i) {
    const int m = m0 + wr*64 + i*16 + fr;
    if constexpr (MODE == 0) {
      short* qs = (short*)out0;
      const int sec = n0 >> 7;
      const float scl = (sec == 0) ? SCALE : 1.0f;
      const int wid = m >> 8, ntok = m & 255;
      const int rowbase = sec*8388608 + (wid*8)*4096 + ntok*16 + (nbb & 15);
#pragma unroll
      for (int j = 0; j < 4; ++j) {
        const int head = ((nbb + j*16) >> 4) & 7;
        f32x4 v = acc[i][j];
        s16x4 o;
        o[0] = f2b(fmaf(v[0], scl, bj4[j].x*scl));
        o[1] = f2b(fmaf(v[1], scl, bj4[j].y*scl));
        o[2] = f2b(fmaf(v[2], scl, bj4[j].z*scl));
        o[3] = f2b(fmaf(v[3], scl, bj4[j].w*scl));
        *(s16x4*)&qs[rowbase + head*4096] = o;
      }
    } else if constexpr (MODE == 1) {
      short* y1o = (short*)out0;       // PADDED [18][34][34][4][128]
      const int wid = m >> 8, ntok = m & 255;
      const int t = ntok >> 6, gd = (ntok >> 4) & 3, gh = (ntok >> 2) & 3, gw = ntok & 3;
      const int wd = wid >> 6, wh = (wid >> 3) & 7, ww = wid & 7;
      const int sr = (((wd*4 + gd + 1)*PH + wh*4 + gh + 1)*PW + ww*4 + gw + 1)*4 + t;
      const int base = sr*CC + nbb;
#pragma unroll
      for (int j = 0; j < 4; ++j) {
        f32x4 v = acc[i][j];
        s16x4 o;
        o[0] = f2b(v[0] + bj4[j].x); o[1] = f2b(v[1] + bj4[j].y);
        o[2] = f2b(v[2] + bj4[j].z); o[3] = f2b(v[3] + bj4[j].w);
        *(s16x4*)&y1o[base + j*16] = o;
      }
    } else if constexpr (MODE == 2) {
      short* gp = (short*)out0;
      const int base = m*512 + nbb;
#pragma unroll
      for (int j = 0; j < 4; ++j) {
        f32x4 v = acc[i][j];
        s16x4 o;
        o[0] = f2b(fast_gelu(v[0] + bj4[j].x)); o[1] = f2b(fast_gelu(v[1] + bj4[j].y));
        o[2] = f2b(fast_gelu(v[2] + bj4[j].z)); o[3] = f2b(fast_gelu(v[3] + bj4[j].w));
        *(s16x4*)&gp[base + j*16] = o;
      }
    } else {
      float* outp = (float*)out0;
      const int base = m*CC + nbb;
#pragma unroll
      for (int j = 0; j < 4; ++j) {
        f32x4 v = acc[i][j];
        f16x4 rz = *(const f16x4*)&resid[base + j*16];
        f32x4 o;
        o.x = v[0] + bj4[j].x + (float)rz[0]; o.y = v[1] + bj4[j].y + (float)rz[1];
        o.z = v[2] + bj4[j].z + (float)rz[2]; o.w = v[3] + bj4[j].w + (float)rz[3];
        *(f32x4*)&outp[base + j*16] = o;
      }
    }
  }
}

// ---------------------------------------------------------------------------
// Kernel: MFMA window attention (unchanged from R2).
// ---------------------------------------------------------------------------
#define KPAD 20
#define VPAD 264
__global__ __launch_bounds__(256) void attn_mfma_kernel(
    const __hip_bfloat16* __restrict__ qb, const __hip_bfloat16* __restrict__ kb,
    const __hip_bfloat16* __restrict__ vb, __hip_bfloat16* __restrict__ ob) {
  __shared__ __align__(16) short kL[256*KPAD];
  __shared__ __align__(16) short vT[16*VPAD];
  const int bh = blockIdx.x;                // win*8 + head
  const int wid = bh >> 3, head = bh & 7;
  const int tid = threadIdx.x;
  const short* kg = (const short*)kb + (size_t)bh*4096;
  const short* vg = (const short*)vb + (size_t)bh*4096;
  const short* qg = (const short*)qb + (size_t)bh*4096;
  {
    s16x8 a0 = *(const s16x8*)&kg[tid*16];
    s16x8 a1 = *(const s16x8*)&kg[tid*16 + 8];
    *(s16x8*)&kL[tid*KPAD]     = a0;
    *(s16x8*)&kL[tid*KPAD + 8] = a1;
    s16x8 b0 = *(const s16x8*)&vg[tid*16];
    s16x8 b1 = *(const s16x8*)&vg[tid*16 + 8];
#pragma unroll
    for (int d = 0; d < 8; ++d) {
      vT[d*VPAD + tid]     = b0[d];
      vT[(d+8)*VPAD + tid] = b1[d];
    }
  }
  __syncthreads();
  const int wv = tid >> 6, lane = tid & 63;
  const int fr = lane & 15, hi = lane >> 4;
  s16x4 kfrag[16], vfrag[16];
#pragma unroll
  for (int t = 0; t < 16; ++t) {
    kfrag[t] = *(const s16x4*)&kL[(t*16 + fr)*KPAD + hi*4];
    vfrag[t] = *(const s16x4*)&vT[fr*VPAD + t*16 + hi*4];
  }
  short* obs = (short*)ob;
  for (int qt = 0; qt < 4; ++qt) {
    const int q0 = wv*64 + qt*16;
    s16x4 qfrag = *(const s16x4*)&qg[(q0 + fr)*16 + hi*4];
    f32x4 st[16];
#pragma unroll
    for (int kt = 0; kt < 16; ++kt)
      st[kt] = mfma16x16x16_bf16(kfrag[kt], qfrag, (f32x4)0.f);
    float den = 0.f;
    f32x4 oacc = (f32x4)0.f;
#pragma unroll
    for (int kt = 0; kt < 16; ++kt) {
      float e0 = __expf(st[kt][0]), e1 = __expf(st[kt][1]);
      float e2 = __expf(st[kt][2]), e3 = __expf(st[kt][3]);
      den += (e0 + e1) + (e2 + e3);
      s16x4 pa;
      pa[0] = f2b(e0); pa[1] = f2b(e1); pa[2] = f2b(e2); pa[3] = f2b(e3);
      oacc = mfma16x16x16_bf16(vfrag[kt], pa, oacc);
    }
    den += __shfl_xor(den, 16);
    den += __shfl_xor(den, 32);
    float inv = 1.f / den;
    s16x4 ov;
    ov[0] = f2b(oacc[0]*inv); ov[1] = f2b(oacc[1]*inv);
    ov[2] = f2b(oacc[2]*inv); ov[3] = f2b(oacc[3]*inv);
    *(s16x4*)&obs[((size_t)wid*256 + q0 + fr)*CC + head*16 + hi*4] = ov;
  }
}

// ---------------------------------------------------------------------------
// Kernel: FUSED conv3x3x3 (padded, branch-free) + exln + norm2.
// thread = (token, c8). __launch_bounds__(256,1): VGPR budget 512 + ILP
// scheduling. All 27 tap loads issued, then a memory-clobber fence pins them
// before the FMA block (compiler cannot sink loads past the clobber).
// ---------------------------------------------------------------------------
__global__ __launch_bounds__(256, 1) void conv_ln_kernel(
    const __hip_bfloat16* __restrict__ y1p, const float* __restrict__ wT,
    const float* __restrict__ cb,
    const float* __restrict__ exg, const float* __restrict__ exb,
    const float* __restrict__ n2g, const float* __restrict__ n2b,
    _Float16* __restrict__ yb, __hip_bfloat16* __restrict__ h2) {
  const int tid = threadIdx.x;
  const int tk = blockIdx.x*16 + (tid >> 4);     // token 0..65535
  const int cbase = (tid & 15) * 8;              // 8-channel group
  const int t = tk & 3, sp = tk >> 2;
  const int w = sp & 31, h = (sp >> 5) & 31, d = sp >> 10;
  const int psite = ((d+1)*PH + (h+1))*PW + (w+1);
  const short* base = (const short*)y1p + (size_t)psite*512 + t*CC + cbase;

  // ---- phase 1: issue ALL 27 tap loads ----
  s16x8 v[27];
#pragma unroll
  for (int dd = 0; dd < 3; ++dd)
#pragma unroll
    for (int dh = 0; dh < 3; ++dh)
#pragma unroll
      for (int dw = 0; dw < 3; ++dw) {
        const int tap = (dd*3 + dh)*3 + dw;
        const int toff = (((dd-1)*PH + (dh-1))*PW + (dw-1))*512;
        v[tap] = *(const s16x8*)(base + toff);
      }
  // fence: loads may not sink below this point
  asm volatile("" ::: "memory");

  // ---- phase 2: FMA block ----
  float acc[8];
  {
    f32x4 cb0 = *(const f32x4*)&cb[cbase];
    f32x4 cb1 = *(const f32x4*)&cb[cbase + 4];
    acc[0]=cb0.x; acc[1]=cb0.y; acc[2]=cb0.z; acc[3]=cb0.w;
    acc[4]=cb1.x; acc[5]=cb1.y; acc[6]=cb1.z; acc[7]=cb1.w;
  }
#pragma unroll
  for (int tap = 0; tap < 27; ++tap) {
    f32x4 w0 = *(const f32x4*)&wT[tap*CC + cbase];
    f32x4 w1 = *(const f32x4*)&wT[tap*CC + cbase + 4];
    acc[0] = fmaf(b2f(v[tap][0]), w0.x, acc[0]);
    acc[1] = fmaf(b2f(v[tap][1]), w0.y, acc[1]);
    acc[2] = fmaf(b2f(v[tap][2]), w0.z, acc[2]);
    acc[3] = fmaf(b2f(v[tap][3]), w0.w, acc[3]);
    acc[4] = fmaf(b2f(v[tap][4]), w1.x, acc[4]);
    acc[5] = fmaf(b2f(v[tap][5]), w1.y, acc[5]);
    acc[6] = fmaf(b2f(v[tap][6]), w1.z, acc[6]);
    acc[7] = fmaf(b2f(v[tap][7]), w1.w, acc[7]);
  }

  f32x4 eg0 = *(const f32x4*)&exg[cbase], eg1 = *(const f32x4*)&exg[cbase+4];
  f32x4 eb0 = *(const f32x4*)&exb[cbase], eb1 = *(const f32x4*)&exb[cbase+4];
  f32x4 ng0 = *(const f32x4*)&n2g[cbase], ng1 = *(const f32x4*)&n2g[cbase+4];
  f32x4 nb0 = *(const f32x4*)&n2b[cbase], nb1 = *(const f32x4*)&n2b[cbase+4];
  float eg[8] = {eg0.x,eg0.y,eg0.z,eg0.w,eg1.x,eg1.y,eg1.z,eg1.w};
  float eb[8] = {eb0.x,eb0.y,eb0.z,eb0.w,eb1.x,eb1.y,eb1.z,eb1.w};
  float ng[8] = {ng0.x,ng0.y,ng0.z,ng0.w,ng1.x,ng1.y,ng1.z,ng1.w};
  float nb[8] = {nb0.x,nb0.y,nb0.z,nb0.w,nb1.x,nb1.y,nb1.z,nb1.w};

  float s = 0.f, sq = 0.f;
#pragma unroll
  for (int c = 0; c < 8; ++c) { s += acc[c]; sq = fmaf(acc[c], acc[c], sq); }
#pragma unroll
  for (int m = 1; m <= 8; m <<= 1) { s += __shfl_xor(s, m); sq += __shfl_xor(sq, m); }
  float mean = s * (1.f/128.f);
  float var  = sq * (1.f/128.f) - mean*mean;
  float rstd = rsqrtf(var + LNEPS);
  float y[8];
  f16x8 yo;
#pragma unroll
  for (int c = 0; c < 8; ++c) {
    y[c] = (acc[c] - mean)*rstd*eg[c] + eb[c];
    yo[c] = (_Float16)y[c];
  }
  *(f16x8*)&yb[(size_t)tk*CC + cbase] = yo;
  float s2 = 0.f, sq2 = 0.f;
#pragma unroll
  for (int c = 0; c < 8; ++c) { s2 += y[c]; sq2 = fmaf(y[c], y[c], sq2); }
#pragma unroll
  for (int m = 1; m <= 8; m <<= 1) { s2 += __shfl_xor(s2, m); sq2 += __shfl_xor(sq2, m); }
  float mean2 = s2 * (1.f/128.f);
  float var2  = sq2 * (1.f/128.f) - mean2*mean2;
  float rstd2 = rsqrtf(var2 + LNEPS);
  s16x8 ho;
#pragma unroll
  for (int c = 0; c < 8; ++c)
    ho[c] = f2b((y[c] - mean2)*rstd2*ng[c] + nb[c]);
  *(s16x8*)&((short*)h2)[(size_t)tk*CC + cbase] = ho;
}

// ---------------------------------------------------------------------------
// Launch
// ---------------------------------------------------------------------------
extern "C" void kernel_launch(void* const* d_in, const int* in_sizes, int n_in,
                              void* d_out, int out_size, void* d_ws, size_t ws_size,
                              hipStream_t stream) {
  const float* x      = (const float*)d_in[0];
  const float* n1g    = (const float*)d_in[1];
  const float* n1b    = (const float*)d_in[2];
  const float* pos    = (const float*)d_in[3];
  const float* te     = (const float*)d_in[4];
  const float* qkv_w  = (const float*)d_in[5];
  const float* qkv_b  = (const float*)d_in[6];
  const float* proj_w = (const float*)d_in[7];
  const float* proj_b = (const float*)d_in[8];
  const float* conv_w = (const float*)d_in[9];
  const float* conv_b = (const float*)d_in[10];
  const float* exg    = (const float*)d_in[11];
  const float* exb    = (const float*)d_in[12];
  const float* n2g    = (const float*)d_in[13];
  const float* n2b    = (const float*)d_in[14];
  const float* fc1_w  = (const float*)d_in[15];
  const float* fc1_b  = (const float*)d_in[16];
  const float* fc2_w  = (const float*)d_in[17];
  const float* fc2_b  = (const float*)d_in[18];

  char* wsb = (char*)d_ws;
  __hip_bfloat16* wq  = (__hip_bfloat16*)(wsb);             // 384x128
  __hip_bfloat16* wp  = (__hip_bfloat16*)(wsb + 98304);     // 128x128
  __hip_bfloat16* w1  = (__hip_bfloat16*)(wsb + 131072);    // 512x128
  __hip_bfloat16* w2  = (__hip_bfloat16*)(wsb + 262144);    // 128x512
  float*          cwT = (float*)(wsb + 393216);             // 27x128

  const size_t A_OFF = (size_t)1 << 20;                     // 16 MiB region
  const size_t B_OFF = A_OFF + ((size_t)16 << 20);          // 48 MiB region
  const size_t C_OFF = B_OFF + ((size_t)48 << 20);          // 64 MiB region

  __hip_bfloat16* hbuf = (__hip_bfloat16*)(wsb + A_OFF);    // LN1 out
  __hip_bfloat16* obuf = (__hip_bfloat16*)(wsb + A_OFF);    // attn out (reuses A)
  __hip_bfloat16* h2in = (__hip_bfloat16*)(wsb + A_OFF);    // MLP in (reuses A)
  __hip_bfloat16* qkvb = (__hip_bfloat16*)(wsb + B_OFF);    // q|k|v, 16MiB each
  __hip_bfloat16* qb   = qkvb;
  __hip_bfloat16* kb   = qkvb + 8388608;
  __hip_bfloat16* vb   = qkvb + 16777216;
  __hip_bfloat16* y1p  = (__hip_bfloat16*)(wsb + B_OFF);    // padded proj out (20.3 MiB, over q+k)
  _Float16* yb = (_Float16*)(wsb + B_OFF + ((size_t)24 << 20)); // fp16 y (16 MiB)
  __hip_bfloat16* gbuf = (__hip_bfloat16*)(wsb + C_OFF);    // GELU out (64 MiB)

  prep_kernel<<<782, 256, 0, stream>>>(qkv_w, proj_w, fc1_w, fc2_w, conv_w,
                                       wq, wp, w1, w2, cwT);
  ln1_pe_kernel<<<TOKS/4, 256, 0, stream>>>(x, n1g, n1b, pos, te, hbuf);
  gemm_kernel<0, 128><<<dim3(TOKS/128, 3), 256, 0, stream>>>(
      (const short*)hbuf, (const short*)wq, qkv_b, (void*)qkvb, nullptr);
  attn_mfma_kernel<<<NWIN*8, 256, 0, stream>>>(qb, kb, vb, obuf);
  border_zero_kernel<<<(PSITES*64 + 255)/256, 256, 0, stream>>>((short*)y1p);
  gemm_kernel<1, 128><<<dim3(TOKS/128, 1), 256, 0, stream>>>(
      (const short*)obuf, (const short*)wp, proj_b, (void*)y1p, nullptr);
  conv_ln_kernel<<<TOKS*16/256, 256, 0, stream>>>(y1p, cwT, conv_b,
      exg, exb, n2g, n2b, yb, h2in);
  gemm_kernel<2, 128><<<dim3(TOKS/128, 4), 256, 0, stream>>>(
      (const short*)h2in, (const short*)w1, fc1_b, (void*)gbuf, nullptr);
  gemm_kernel<3, 512><<<dim3(TOKS/128, 1), 256, 0, stream>>>(
      (const short*)gbuf, (const short*)w2, fc2_b, (void*)d_out, yb);
}

// Round 12
// 179.753 us; speedup vs baseline: 1.0583x; 1.0583x over previous
//
#include <hip/hip_runtime.h>
#include <hip/hip_bf16.h>

// ---------------------------------------------------------------------------
// CrossFormerBlock on MI355X (gfx950)
// B=1 D=16 H=32 W=32 T=4 C=128, G=4, NH=8, HD=16, NW=256 windows, N=256 tok/win
// R12: conv_ln reverted to R8's proven structure (site/c8 mapping, 4 t-chains,
// VGPR 92, 39.4 us measured) + R9's border_zero kernel (~3 us) instead of the
// 39.6 us memset. No other changes — exposes the GEMM/attn tier for R13.
// ---------------------------------------------------------------------------

typedef __attribute__((ext_vector_type(8))) short  s16x8;
typedef __attribute__((ext_vector_type(4))) short  s16x4;
typedef __attribute__((ext_vector_type(4))) float  f32x4;
typedef __attribute__((ext_vector_type(8))) _Float16 f16x8;
typedef __attribute__((ext_vector_type(4))) _Float16 f16x4;

#define CC    128
#define NWIN  256
#define TOKS  65536            // total tokens = D*H*W*T
#define SCALE 0.25f
#define LNEPS 1e-5f
// padded spatial geometry for conv
#define PD 18
#define PH 34
#define PW 34
#define PSITES (PD*PH*PW)                // 20808
#define Y1P_SHORTS ((size_t)PSITES*512)  // *4t*128c

__device__ __forceinline__ float b2f(short s) {
  union { unsigned u; float f; } c; c.u = ((unsigned)(unsigned short)s) << 16; return c.f;
}
__device__ __forceinline__ short f2b(float f) {
  __hip_bfloat16 h = __float2bfloat16(f);
  return *reinterpret_cast<short*>(&h);
}
__device__ __forceinline__ float fast_gelu(float x) {
  float u = 1.595769122f * x * fmaf(0.044715f, x*x, 1.0f);
  return x / (1.0f + __expf(-u));
}

__device__ __forceinline__ f32x4 mfma16x16x16_bf16(s16x4 a, s16x4 b, f32x4 c) {
#if __has_builtin(__builtin_amdgcn_mfma_f32_16x16x16_bf16)
  return __builtin_amdgcn_mfma_f32_16x16x16_bf16(a, b, c, 0, 0, 0);
#elif __has_builtin(__builtin_amdgcn_mfma_f32_16x16x16bf16_1k)
  return __builtin_amdgcn_mfma_f32_16x16x16bf16_1k(a, b, c, 0, 0, 0);
#else
  f32x4 d;
  asm("v_mfma_f32_16x16x16_bf16 %0, %1, %2, %3" : "=v"(d) : "v"(a), "v"(b), "v"(c));
  return d;
#endif
}

// ---------------------------------------------------------------------------
// Kernel 0: weight prep
// ---------------------------------------------------------------------------
__global__ void prep_kernel(const float* __restrict__ qkv_w, const float* __restrict__ proj_w,
                            const float* __restrict__ fc1_w, const float* __restrict__ fc2_w,
                            const float* __restrict__ conv_w,
                            __hip_bfloat16* wq, __hip_bfloat16* wp,
                            __hip_bfloat16* w1, __hip_bfloat16* w2, float* cwT) {
  int idx = blockIdx.x * 256 + threadIdx.x;
  if (idx < 49152) {
    wq[idx] = __float2bfloat16(qkv_w[idx]);
  } else if (idx < 65536) {
    wp[idx - 49152] = __float2bfloat16(proj_w[idx - 49152]);
  } else if (idx < 131072) {
    w1[idx - 65536] = __float2bfloat16(fc1_w[idx - 65536]);
  } else if (idx < 196608) {
    w2[idx - 131072] = __float2bfloat16(fc2_w[idx - 131072]);
  } else if (idx < 196608 + 27*128) {
    int j = idx - 196608;
    int tap = j >> 7, c = j & 127;
    cwT[tap*128 + c] = conv_w[c*27 + tap];   // (C,1,3,3,3) -> (27,C)
  }
}

// ---------------------------------------------------------------------------
// Kernel: zero only the BORDER sites of the padded y1 buffer (4424 sites).
// ---------------------------------------------------------------------------
__global__ __launch_bounds__(256) void border_zero_kernel(short* __restrict__ y1p) {
  int idx = blockIdx.x*256 + threadIdx.x;
  if (idx >= PSITES*64) return;
  int site = idx >> 6;
  int w = site % PW, hh = (site / PW) % PH, d = site / (PW*PH);
  if (d != 0 && d != PD-1 && hh != 0 && hh != PH-1 && w != 0 && w != PW-1) return;
  *(s16x8*)&y1p[(size_t)site*512 + (idx & 63)*8] = (s16x8)0;
}

// ---------------------------------------------------------------------------
// Kernel 1: LN1 + positional/temporal embed -> window-token layout bf16
// ---------------------------------------------------------------------------
__global__ __launch_bounds__(256) void ln1_pe_kernel(
    const float* __restrict__ x, const float* __restrict__ g, const float* __restrict__ b,
    const float* __restrict__ pos, const float* __restrict__ te,
    __hip_bfloat16* __restrict__ hb) {
  int wv = threadIdx.x >> 6, lane = threadIdx.x & 63;
  int tk = blockIdx.x * 4 + wv;                 // tk = wid*256 + n
  int wid = tk >> 8, n = tk & 255;
  int t = n >> 6, gd = (n >> 4) & 3, gh = (n >> 2) & 3, gw = n & 3;
  int wd = wid >> 6, wh = (wid >> 3) & 7, ww = wid & 7;
  int d = wd*4 + gd, h = wh*4 + gh, w = ww*4 + gw;
  size_t xoff = ((size_t)((d*32 + h)*32 + w)*4 + t) * CC;
  float v0 = x[xoff + lane], v1 = x[xoff + lane + 64];
  float s = v0 + v1, sq = v0*v0 + v1*v1;
  for (int m = 32; m; m >>= 1) { s += __shfl_xor(s, m); sq += __shfl_xor(sq, m); }
  float mean = s * (1.f/128.f);
  float var  = sq * (1.f/128.f) - mean*mean;
  float rstd = rsqrtf(var + LNEPS);
  int pb = ((gd*4 + gh)*4 + gw) * CC, tb = t * CC;
  float h0 = (v0 - mean)*rstd*g[lane]    + b[lane]    + pos[pb + lane]    + te[tb + lane];
  float h1 = (v1 - mean)*rstd*g[lane+64] + b[lane+64] + pos[pb + lane+64] + te[tb + lane+64];
  hb[(size_t)tk*CC + lane]      = __float2bfloat16(h0);
  hb[(size_t)tk*CC + lane + 64] = __float2bfloat16(h1);
}

// ---------------------------------------------------------------------------
// GEMM template: 128x128 tile, BK=64, 4 waves, compile-time K (KK).
// acc[i][j] = mfma(b[j], a[i], acc) -> D^T fragments (vector stores).
// ---------------------------------------------------------------------------
template <int MODE, int KK>
__global__ __launch_bounds__(256) void gemm_kernel(
    const short* __restrict__ Ag, const short* __restrict__ Wg,
    const float* __restrict__ bias,
    void* __restrict__ out0, const _Float16* __restrict__ resid) {
  __shared__ __align__(16) short As[128*72];
  __shared__ __align__(16) short Bs[128*72];
  const int tid = threadIdx.x;
  const int m0 = blockIdx.x * 128;
  const int n0 = blockIdx.y * 128;
  const int lane = tid & 63, wv = tid >> 6;
  const int wr = wv >> 1, wc = wv & 1;
  const int fr = lane & 15, kg = lane >> 4;

  f32x4 acc[4][4];
#pragma unroll
  for (int i = 0; i < 4; ++i)
#pragma unroll
    for (int j = 0; j < 4; ++j) acc[i][j] = (f32x4)0.f;

#pragma unroll
  for (int kc = 0; kc < KK; kc += 64) {
    __syncthreads();
#pragma unroll
    for (int i = 0; i < 4; ++i) {
      int c = tid + i*256;
      int row = c >> 3, col8 = (c & 7) * 8;
      s16x8 va = *(const s16x8*)(Ag + (size_t)(m0 + row)*KK + kc + col8);
      s16x8 vb = *(const s16x8*)(Wg + (size_t)(n0 + row)*KK + kc + col8);
      *(s16x8*)&As[row*72 + col8] = va;
      *(s16x8*)&Bs[row*72 + col8] = vb;
    }
    __syncthreads();
#pragma unroll
    for (int ks = 0; ks < 2; ++ks) {
      s16x8 a[4], b[4];
#pragma unroll
      for (int i = 0; i < 4; ++i)
        a[i] = *(const s16x8*)&As[(wr*64 + i*16 + fr)*72 + ks*32 + kg*8];
#pragma unroll
      for (int j = 0; j < 4; ++j)
        b[j] = *(const s16x8*)&Bs[(wc*64 + j*16 + fr)*72 + ks*32 + kg*8];
#pragma unroll
      for (int i = 0; i < 4; ++i)
#pragma unroll
        for (int j = 0; j < 4; ++j)
          acc[i][j] = __builtin_amdgcn_mfma_f32_16x16x32_bf16(b[j], a[i], acc[i][j], 0, 0, 0);
    }
  }

  const int nbb = n0 + wc*64 + kg*4;
  f32x4 bj4[4];
#pragma unroll
  for (int j = 0; j < 4; ++j) bj4[j] = *(const f32x4*)&bias[nbb + j*16];

#pragma unroll
  for (int i = 0; i < 4; ++i) {
    const int m = m0 + wr*64 + i*16 + fr;
    if constexpr (MODE == 0) {
      short* qs = (short*)out0;
      const int sec = n0 >> 7;
      const float scl = (sec == 0) ? SCALE : 1.0f;
      const int wid = m >> 8, ntok = m & 255;
      const int rowbase = sec*8388608 + (wid*8)*4096 + ntok*16 + (nbb & 15);
#pragma unroll
      for (int j = 0; j < 4; ++j) {
        const int head = ((nbb + j*16) >> 4) & 7;
        f32x4 v = acc[i][j];
        s16x4 o;
        o[0] = f2b(fmaf(v[0], scl, bj4[j].x*scl));
        o[1] = f2b(fmaf(v[1], scl, bj4[j].y*scl));
        o[2] = f2b(fmaf(v[2], scl, bj4[j].z*scl));
        o[3] = f2b(fmaf(v[3], scl, bj4[j].w*scl));
        *(s16x4*)&qs[rowbase + head*4096] = o;
      }
    } else if constexpr (MODE == 1) {
      short* y1o = (short*)out0;       // PADDED [18][34][34][4][128]
      const int wid = m >> 8, ntok = m & 255;
      const int t = ntok >> 6, gd = (ntok >> 4) & 3, gh = (ntok >> 2) & 3, gw = ntok & 3;
      const int wd = wid >> 6, wh = (wid >> 3) & 7, ww = wid & 7;
      const int sr = (((wd*4 + gd + 1)*PH + wh*4 + gh + 1)*PW + ww*4 + gw + 1)*4 + t;
      const int base = sr*CC + nbb;
#pragma unroll
      for (int j = 0; j < 4; ++j) {
        f32x4 v = acc[i][j];
        s16x4 o;
        o[0] = f2b(v[0] + bj4[j].x); o[1] = f2b(v[1] + bj4[j].y);
        o[2] = f2b(v[2] + bj4[j].z); o[3] = f2b(v[3] + bj4[j].w);
        *(s16x4*)&y1o[base + j*16] = o;
      }
    } else if constexpr (MODE == 2) {
      short* gp = (short*)out0;
      const int base = m*512 + nbb;
#pragma unroll
      for (int j = 0; j < 4; ++j) {
        f32x4 v = acc[i][j];
        s16x4 o;
        o[0] = f2b(fast_gelu(v[0] + bj4[j].x)); o[1] = f2b(fast_gelu(v[1] + bj4[j].y));
        o[2] = f2b(fast_gelu(v[2] + bj4[j].z)); o[3] = f2b(fast_gelu(v[3] + bj4[j].w));
        *(s16x4*)&gp[base + j*16] = o;
      }
    } else {
      float* outp = (float*)out0;
      const int base = m*CC + nbb;
#pragma unroll
      for (int j = 0; j < 4; ++j) {
        f32x4 v = acc[i][j];
        f16x4 rz = *(const f16x4*)&resid[base + j*16];
        f32x4 o;
        o.x = v[0] + bj4[j].x + (float)rz[0]; o.y = v[1] + bj4[j].y + (float)rz[1];
        o.z = v[2] + bj4[j].z + (float)rz[2]; o.w = v[3] + bj4[j].w + (float)rz[3];
        *(f32x4*)&outp[base + j*16] = o;
      }
    }
  }
}

// ---------------------------------------------------------------------------
// Kernel: MFMA window attention (unchanged from R2).
// ---------------------------------------------------------------------------
#define KPAD 20
#define VPAD 264
__global__ __launch_bounds__(256) void attn_mfma_kernel(
    const __hip_bfloat16* __restrict__ qb, const __hip_bfloat16* __restrict__ kb,
    const __hip_bfloat16* __restrict__ vb, __hip_bfloat16* __restrict__ ob) {
  __shared__ __align__(16) short kL[256*KPAD];
  __shared__ __align__(16) short vT[16*VPAD];
  const int bh = blockIdx.x;                // win*8 + head
  const int wid = bh >> 3, head = bh & 7;
  const int tid = threadIdx.x;
  const short* kg = (const short*)kb + (size_t)bh*4096;
  const short* vg = (const short*)vb + (size_t)bh*4096;
  const short* qg = (const short*)qb + (size_t)bh*4096;
  {
    s16x8 a0 = *(const s16x8*)&kg[tid*16];
    s16x8 a1 = *(const s16x8*)&kg[tid*16 + 8];
    *(s16x8*)&kL[tid*KPAD]     = a0;
    *(s16x8*)&kL[tid*KPAD + 8] = a1;
    s16x8 b0 = *(const s16x8*)&vg[tid*16];
    s16x8 b1 = *(const s16x8*)&vg[tid*16 + 8];
#pragma unroll
    for (int d = 0; d < 8; ++d) {
      vT[d*VPAD + tid]     = b0[d];
      vT[(d+8)*VPAD + tid] = b1[d];
    }
  }
  __syncthreads();
  const int wv = tid >> 6, lane = tid & 63;
  const int fr = lane & 15, hi = lane >> 4;
  s16x4 kfrag[16], vfrag[16];
#pragma unroll
  for (int t = 0; t < 16; ++t) {
    kfrag[t] = *(const s16x4*)&kL[(t*16 + fr)*KPAD + hi*4];
    vfrag[t] = *(const s16x4*)&vT[fr*VPAD + t*16 + hi*4];
  }
  short* obs = (short*)ob;
  for (int qt = 0; qt < 4; ++qt) {
    const int q0 = wv*64 + qt*16;
    s16x4 qfrag = *(const s16x4*)&qg[(q0 + fr)*16 + hi*4];
    f32x4 st[16];
#pragma unroll
    for (int kt = 0; kt < 16; ++kt)
      st[kt] = mfma16x16x16_bf16(kfrag[kt], qfrag, (f32x4)0.f);
    float den = 0.f;
    f32x4 oacc = (f32x4)0.f;
#pragma unroll
    for (int kt = 0; kt < 16; ++kt) {
      float e0 = __expf(st[kt][0]), e1 = __expf(st[kt][1]);
      float e2 = __expf(st[kt][2]), e3 = __expf(st[kt][3]);
      den += (e0 + e1) + (e2 + e3);
      s16x4 pa;
      pa[0] = f2b(e0); pa[1] = f2b(e1); pa[2] = f2b(e2); pa[3] = f2b(e3);
      oacc = mfma16x16x16_bf16(vfrag[kt], pa, oacc);
    }
    den += __shfl_xor(den, 16);
    den += __shfl_xor(den, 32);
    float inv = 1.f / den;
    s16x4 ov;
    ov[0] = f2b(oacc[0]*inv); ov[1] = f2b(oacc[1]*inv);
    ov[2] = f2b(oacc[2]*inv); ov[3] = f2b(oacc[3]*inv);
    *(s16x4*)&obs[((size_t)wid*256 + q0 + fr)*CC + head*16 + hi*4] = ov;
  }
}

// ---------------------------------------------------------------------------
// Kernel: FUSED conv3x3x3 (padded bf16 in, NO guards) + exln + norm2.
// R8's proven structure: thread = (site, c8-group): 16 threads/site, 8 ch
// each, 4 independent t-chains -> compiler batches loads (VGPR 92).
// ---------------------------------------------------------------------------
__global__ __launch_bounds__(256) void conv_ln_kernel(
    const __hip_bfloat16* __restrict__ y1p, const float* __restrict__ wT,
    const float* __restrict__ cb,
    const float* __restrict__ exg, const float* __restrict__ exb,
    const float* __restrict__ n2g, const float* __restrict__ n2b,
    _Float16* __restrict__ yb, __hip_bfloat16* __restrict__ h2) {
  const int tid = threadIdx.x;
  const int sp = blockIdx.x*16 + (tid >> 4);     // spatial site 0..16383
  const int cbase = (tid & 15) * 8;              // 8-channel group
  const int w = sp & 31, h = (sp >> 5) & 31, d = sp >> 10;
  const int psite = ((d+1)*PH + (h+1))*PW + (w+1);
  const short* base = (const short*)y1p + (size_t)psite*512 + cbase;

  float acc[4][8];
  {
    f32x4 cb0 = *(const f32x4*)&cb[cbase];
    f32x4 cb1 = *(const f32x4*)&cb[cbase + 4];
#pragma unroll
    for (int t = 0; t < 4; ++t) {
      acc[t][0]=cb0.x; acc[t][1]=cb0.y; acc[t][2]=cb0.z; acc[t][3]=cb0.w;
      acc[t][4]=cb1.x; acc[t][5]=cb1.y; acc[t][6]=cb1.z; acc[t][7]=cb1.w;
    }
  }

#pragma unroll
  for (int dd = -1; dd <= 1; ++dd)
#pragma unroll
    for (int dh = -1; dh <= 1; ++dh)
#pragma unroll
      for (int dw = -1; dw <= 1; ++dw) {
        const int tap = ((dd+1)*3 + (dh+1))*3 + (dw+1);
        const int toff = ((dd*PH + dh)*PW + dw)*512;
        f32x4 w0 = *(const f32x4*)&wT[tap*CC + cbase];
        f32x4 w1 = *(const f32x4*)&wT[tap*CC + cbase + 4];
#pragma unroll
        for (int t = 0; t < 4; ++t) {
          s16x8 v = *(const s16x8*)(base + toff + t*CC);
          acc[t][0] = fmaf(b2f(v[0]), w0.x, acc[t][0]);
          acc[t][1] = fmaf(b2f(v[1]), w0.y, acc[t][1]);
          acc[t][2] = fmaf(b2f(v[2]), w0.z, acc[t][2]);
          acc[t][3] = fmaf(b2f(v[3]), w0.w, acc[t][3]);
          acc[t][4] = fmaf(b2f(v[4]), w1.x, acc[t][4]);
          acc[t][5] = fmaf(b2f(v[5]), w1.y, acc[t][5]);
          acc[t][6] = fmaf(b2f(v[6]), w1.z, acc[t][6]);
          acc[t][7] = fmaf(b2f(v[7]), w1.w, acc[t][7]);
        }
      }

  f32x4 eg0 = *(const f32x4*)&exg[cbase], eg1 = *(const f32x4*)&exg[cbase+4];
  f32x4 eb0 = *(const f32x4*)&exb[cbase], eb1 = *(const f32x4*)&exb[cbase+4];
  f32x4 ng0 = *(const f32x4*)&n2g[cbase], ng1 = *(const f32x4*)&n2g[cbase+4];
  f32x4 nb0 = *(const f32x4*)&n2b[cbase], nb1 = *(const f32x4*)&n2b[cbase+4];
  float eg[8] = {eg0.x,eg0.y,eg0.z,eg0.w,eg1.x,eg1.y,eg1.z,eg1.w};
  float eb[8] = {eb0.x,eb0.y,eb0.z,eb0.w,eb1.x,eb1.y,eb1.z,eb1.w};
  float ng[8] = {ng0.x,ng0.y,ng0.z,ng0.w,ng1.x,ng1.y,ng1.z,ng1.w};
  float nb[8] = {nb0.x,nb0.y,nb0.z,nb0.w,nb1.x,nb1.y,nb1.z,nb1.w};

#pragma unroll
  for (int t = 0; t < 4; ++t) {
    float s = 0.f, sq = 0.f;
#pragma unroll
    for (int c = 0; c < 8; ++c) { s += acc[t][c]; sq = fmaf(acc[t][c], acc[t][c], sq); }
#pragma unroll
    for (int m = 1; m <= 8; m <<= 1) { s += __shfl_xor(s, m); sq += __shfl_xor(sq, m); }
    float mean = s * (1.f/128.f);
    float var  = sq * (1.f/128.f) - mean*mean;
    float rstd = rsqrtf(var + LNEPS);
    float y[8];
    f16x8 yo;
#pragma unroll
    for (int c = 0; c < 8; ++c) {
      y[c] = (acc[t][c] - mean)*rstd*eg[c] + eb[c];
      yo[c] = (_Float16)y[c];
    }
    *(f16x8*)&yb[(size_t)(sp*4 + t)*CC + cbase] = yo;
    float s2 = 0.f, sq2 = 0.f;
#pragma unroll
    for (int c = 0; c < 8; ++c) { s2 += y[c]; sq2 = fmaf(y[c], y[c], sq2); }
#pragma unroll
    for (int m = 1; m <= 8; m <<= 1) { s2 += __shfl_xor(s2, m); sq2 += __shfl_xor(sq2, m); }
    float mean2 = s2 * (1.f/128.f);
    float var2  = sq2 * (1.f/128.f) - mean2*mean2;
    float rstd2 = rsqrtf(var2 + LNEPS);
    s16x8 ho;
#pragma unroll
    for (int c = 0; c < 8; ++c)
      ho[c] = f2b((y[c] - mean2)*rstd2*ng[c] + nb[c]);
    *(s16x8*)&((short*)h2)[(size_t)(sp*4 + t)*CC + cbase] = ho;
  }
}

// ---------------------------------------------------------------------------
// Launch
// ---------------------------------------------------------------------------
extern "C" void kernel_launch(void* const* d_in, const int* in_sizes, int n_in,
                              void* d_out, int out_size, void* d_ws, size_t ws_size,
                              hipStream_t stream) {
  const float* x      = (const float*)d_in[0];
  const float* n1g    = (const float*)d_in[1];
  const float* n1b    = (const float*)d_in[2];
  const float* pos    = (const float*)d_in[3];
  const float* te     = (const float*)d_in[4];
  const float* qkv_w  = (const float*)d_in[5];
  const float* qkv_b  = (const float*)d_in[6];
  const float* proj_w = (const float*)d_in[7];
  const float* proj_b = (const float*)d_in[8];
  const float* conv_w = (const float*)d_in[9];
  const float* conv_b = (const float*)d_in[10];
  const float* exg    = (const float*)d_in[11];
  const float* exb    = (const float*)d_in[12];
  const float* n2g    = (const float*)d_in[13];
  const float* n2b    = (const float*)d_in[14];
  const float* fc1_w  = (const float*)d_in[15];
  const float* fc1_b  = (const float*)d_in[16];
  const float* fc2_w  = (const float*)d_in[17];
  const float* fc2_b  = (const float*)d_in[18];

  char* wsb = (char*)d_ws;
  __hip_bfloat16* wq  = (__hip_bfloat16*)(wsb);             // 384x128
  __hip_bfloat16* wp  = (__hip_bfloat16*)(wsb + 98304);     // 128x128
  __hip_bfloat16* w1  = (__hip_bfloat16*)(wsb + 131072);    // 512x128
  __hip_bfloat16* w2  = (__hip_bfloat16*)(wsb + 262144);    // 128x512
  float*          cwT = (float*)(wsb + 393216);             // 27x128

  const size_t A_OFF = (size_t)1 << 20;                     // 16 MiB region
  const size_t B_OFF = A_OFF + ((size_t)16 << 20);          // 48 MiB region
  const size_t C_OFF = B_OFF + ((size_t)48 << 20);          // 64 MiB region

  __hip_bfloat16* hbuf = (__hip_bfloat16*)(wsb + A_OFF);    // LN1 out
  __hip_bfloat16* obuf = (__hip_bfloat16*)(wsb + A_OFF);    // attn out (reuses A)
  __hip_bfloat16* h2in = (__hip_bfloat16*)(wsb + A_OFF);    // MLP in (reuses A)
  __hip_bfloat16* qkvb = (__hip_bfloat16*)(wsb + B_OFF);    // q|k|v, 16MiB each
  __hip_bfloat16* qb   = qkvb;
  __hip_bfloat16* kb   = qkvb + 8388608;
  __hip_bfloat16* vb   = qkvb + 16777216;
  __hip_bfloat16* y1p  = (__hip_bfloat16*)(wsb + B_OFF);    // padded proj out (20.3 MiB, over q+k)
  _Float16* yb = (_Float16*)(wsb + B_OFF + ((size_t)24 << 20)); // fp16 y (16 MiB)
  __hip_bfloat16* gbuf = (__hip_bfloat16*)(wsb + C_OFF);    // GELU out (64 MiB)

  prep_kernel<<<782, 256, 0, stream>>>(qkv_w, proj_w, fc1_w, fc2_w, conv_w,
                                       wq, wp, w1, w2, cwT);
  ln1_pe_kernel<<<TOKS/4, 256, 0, stream>>>(x, n1g, n1b, pos, te, hbuf);
  gemm_kernel<0, 128><<<dim3(TOKS/128, 3), 256, 0, stream>>>(
      (const short*)hbuf, (const short*)wq, qkv_b, (void*)qkvb, nullptr);
  attn_mfma_kernel<<<NWIN*8, 256, 0, stream>>>(qb, kb, vb, obuf);
  border_zero_kernel<<<(PSITES*64 + 255)/256, 256, 0, stream>>>((short*)y1p);
  gemm_kernel<1, 128><<<dim3(TOKS/128, 1), 256, 0, stream>>>(
      (const short*)obuf, (const short*)wp, proj_b, (void*)y1p, nullptr);
  conv_ln_kernel<<<16384/16, 256, 0, stream>>>(y1p, cwT, conv_b,
      exg, exb, n2g, n2b, yb, h2in);
  gemm_kernel<2, 128><<<dim3(TOKS/128, 4), 256, 0, stream>>>(
      (const short*)h2in, (const short*)w1, fc1_b, (void*)gbuf, nullptr);
  gemm_kernel<3, 512><<<dim3(TOKS/128, 1), 256, 0, stream>>>(
      (const short*)gbuf, (const short*)w2, fc2_b, (void*)d_out, yb);
}

// Round 13
// 173.558 us; speedup vs baseline: 1.0961x; 1.0357x over previous
//
#include <hip/hip_runtime.h>
#include <hip/hip_bf16.h>

// ---------------------------------------------------------------------------
// CrossFormerBlock on MI355X (gfx950)
// B=1 D=16 H=32 W=32 T=4 C=128, G=4, NH=8, HD=16, NW=256 windows, N=256 tok/win
// R13: GEMM staging via __builtin_amdgcn_global_load_lds width=16 (linear LDS
// [128][64], wave-uniform dest + lane*16B; per-lane global src). Removes the
// VGPR round-trip + ds_write VALU that capped the m90-tier template (guide
// m93->m97: +69%). Conv (R8 structure) + border_zero + attention unchanged.
// ---------------------------------------------------------------------------

typedef __attribute__((ext_vector_type(8))) short  s16x8;
typedef __attribute__((ext_vector_type(4))) short  s16x4;
typedef __attribute__((ext_vector_type(4))) float  f32x4;
typedef __attribute__((ext_vector_type(8))) _Float16 f16x8;
typedef __attribute__((ext_vector_type(4))) _Float16 f16x4;

#define CC    128
#define NWIN  256
#define TOKS  65536            // total tokens = D*H*W*T
#define SCALE 0.25f
#define LNEPS 1e-5f
// padded spatial geometry for conv
#define PD 18
#define PH 34
#define PW 34
#define PSITES (PD*PH*PW)                // 20808
#define Y1P_SHORTS ((size_t)PSITES*512)  // *4t*128c

__device__ __forceinline__ float b2f(short s) {
  union { unsigned u; float f; } c; c.u = ((unsigned)(unsigned short)s) << 16; return c.f;
}
__device__ __forceinline__ short f2b(float f) {
  __hip_bfloat16 h = __float2bfloat16(f);
  return *reinterpret_cast<short*>(&h);
}
__device__ __forceinline__ float fast_gelu(float x) {
  float u = 1.595769122f * x * fmaf(0.044715f, x*x, 1.0f);
  return x / (1.0f + __expf(-u));
}

__device__ __forceinline__ f32x4 mfma16x16x16_bf16(s16x4 a, s16x4 b, f32x4 c) {
#if __has_builtin(__builtin_amdgcn_mfma_f32_16x16x16_bf16)
  return __builtin_amdgcn_mfma_f32_16x16x16_bf16(a, b, c, 0, 0, 0);
#elif __has_builtin(__builtin_amdgcn_mfma_f32_16x16x16bf16_1k)
  return __builtin_amdgcn_mfma_f32_16x16x16bf16_1k(a, b, c, 0, 0, 0);
#else
  f32x4 d;
  asm("v_mfma_f32_16x16x16_bf16 %0, %1, %2, %3" : "=v"(d) : "v"(a), "v"(b), "v"(c));
  return d;
#endif
}

// async global->LDS, 16B per lane; lds base must be wave-uniform (HW appends
// lane*16), global src is per-lane.
__device__ __forceinline__ void gload16(const short* g, short* l) {
  __builtin_amdgcn_global_load_lds(
      (const __attribute__((address_space(1))) void*)g,
      (__attribute__((address_space(3))) void*)l, 16, 0, 0);
}

// ---------------------------------------------------------------------------
// Kernel 0: weight prep
// ---------------------------------------------------------------------------
__global__ void prep_kernel(const float* __restrict__ qkv_w, const float* __restrict__ proj_w,
                            const float* __restrict__ fc1_w, const float* __restrict__ fc2_w,
                            const float* __restrict__ conv_w,
                            __hip_bfloat16* wq, __hip_bfloat16* wp,
                            __hip_bfloat16* w1, __hip_bfloat16* w2, float* cwT) {
  int idx = blockIdx.x * 256 + threadIdx.x;
  if (idx < 49152) {
    wq[idx] = __float2bfloat16(qkv_w[idx]);
  } else if (idx < 65536) {
    wp[idx - 49152] = __float2bfloat16(proj_w[idx - 49152]);
  } else if (idx < 131072) {
    w1[idx - 65536] = __float2bfloat16(fc1_w[idx - 65536]);
  } else if (idx < 196608) {
    w2[idx - 131072] = __float2bfloat16(fc2_w[idx - 131072]);
  } else if (idx < 196608 + 27*128) {
    int j = idx - 196608;
    int tap = j >> 7, c = j & 127;
    cwT[tap*128 + c] = conv_w[c*27 + tap];   // (C,1,3,3,3) -> (27,C)
  }
}

// ---------------------------------------------------------------------------
// Kernel: zero only the BORDER sites of the padded y1 buffer (4424 sites).
// ---------------------------------------------------------------------------
__global__ __launch_bounds__(256) void border_zero_kernel(short* __restrict__ y1p) {
  int idx = blockIdx.x*256 + threadIdx.x;
  if (idx >= PSITES*64) return;
  int site = idx >> 6;
  int w = site % PW, hh = (site / PW) % PH, d = site / (PW*PH);
  if (d != 0 && d != PD-1 && hh != 0 && hh != PH-1 && w != 0 && w != PW-1) return;
  *(s16x8*)&y1p[(size_t)site*512 + (idx & 63)*8] = (s16x8)0;
}

// ---------------------------------------------------------------------------
// Kernel 1: LN1 + positional/temporal embed -> window-token layout bf16
// ---------------------------------------------------------------------------
__global__ __launch_bounds__(256) void ln1_pe_kernel(
    const float* __restrict__ x, const float* __restrict__ g, const float* __restrict__ b,
    const float* __restrict__ pos, const float* __restrict__ te,
    __hip_bfloat16* __restrict__ hb) {
  int wv = threadIdx.x >> 6, lane = threadIdx.x & 63;
  int tk = blockIdx.x * 4 + wv;                 // tk = wid*256 + n
  int wid = tk >> 8, n = tk & 255;
  int t = n >> 6, gd = (n >> 4) & 3, gh = (n >> 2) & 3, gw = n & 3;
  int wd = wid >> 6, wh = (wid >> 3) & 7, ww = wid & 7;
  int d = wd*4 + gd, h = wh*4 + gh, w = ww*4 + gw;
  size_t xoff = ((size_t)((d*32 + h)*32 + w)*4 + t) * CC;
  float v0 = x[xoff + lane], v1 = x[xoff + lane + 64];
  float s = v0 + v1, sq = v0*v0 + v1*v1;
  for (int m = 32; m; m >>= 1) { s += __shfl_xor(s, m); sq += __shfl_xor(sq, m); }
  float mean = s * (1.f/128.f);
  float var  = sq * (1.f/128.f) - mean*mean;
  float rstd = rsqrtf(var + LNEPS);
  int pb = ((gd*4 + gh)*4 + gw) * CC, tb = t * CC;
  float h0 = (v0 - mean)*rstd*g[lane]    + b[lane]    + pos[pb + lane]    + te[tb + lane];
  float h1 = (v1 - mean)*rstd*g[lane+64] + b[lane+64] + pos[pb + lane+64] + te[tb + lane+64];
  hb[(size_t)tk*CC + lane]      = __float2bfloat16(h0);
  hb[(size_t)tk*CC + lane + 64] = __float2bfloat16(h1);
}

// ---------------------------------------------------------------------------
// GEMM template: 128x128 tile, BK=64, 4 waves, compile-time K (KK).
// Staging: global_load_lds width=16 into LINEAR LDS [128][64] (wave-uniform
// dest base, per-lane global src). acc[i][j] = mfma(b[j], a[i], acc) -> D^T.
// ---------------------------------------------------------------------------
template <int MODE, int KK>
__global__ __launch_bounds__(256) void gemm_kernel(
    const short* __restrict__ Ag, const short* __restrict__ Wg,
    const float* __restrict__ bias,
    void* __restrict__ out0, const _Float16* __restrict__ resid) {
  __shared__ __align__(16) short As[128*64];
  __shared__ __align__(16) short Bs[128*64];
  const int tid = threadIdx.x;
  const int m0 = blockIdx.x * 128;
  const int n0 = blockIdx.y * 128;
  const int lane = tid & 63, wv = tid >> 6;
  const int wr = wv >> 1, wc = wv & 1;
  const int fr = lane & 15, kg = lane >> 4;

  f32x4 acc[4][4];
#pragma unroll
  for (int i = 0; i < 4; ++i)
#pragma unroll
    for (int j = 0; j < 4; ++j) acc[i][j] = (f32x4)0.f;

#pragma unroll
  for (int kc = 0; kc < KK; kc += 64) {
    __syncthreads();
    // stage A and B tiles: 4 chunks each, 16B/lane, LDS linear [row][64]
#pragma unroll
    for (int i = 0; i < 4; ++i) {
      const int e = i*2048 + tid*8;          // short index in 128x64 tile
      const int row = e >> 6, col = e & 63;
      gload16(Ag + (size_t)(m0 + row)*KK + kc + col, &As[i*2048 + wv*512]);
      gload16(Wg + (size_t)(n0 + row)*KK + kc + col, &Bs[i*2048 + wv*512]);
    }
    __syncthreads();   // compiler drains vmcnt before barrier
#pragma unroll
    for (int ks = 0; ks < 2; ++ks) {
      s16x8 a[4], b[4];
#pragma unroll
      for (int i = 0; i < 4; ++i)
        a[i] = *(const s16x8*)&As[(wr*64 + i*16 + fr)*64 + ks*32 + kg*8];
#pragma unroll
      for (int j = 0; j < 4; ++j)
        b[j] = *(const s16x8*)&Bs[(wc*64 + j*16 + fr)*64 + ks*32 + kg*8];
#pragma unroll
      for (int i = 0; i < 4; ++i)
#pragma unroll
        for (int j = 0; j < 4; ++j)
          acc[i][j] = __builtin_amdgcn_mfma_f32_16x16x32_bf16(b[j], a[i], acc[i][j], 0, 0, 0);
    }
  }

  const int nbb = n0 + wc*64 + kg*4;
  f32x4 bj4[4];
#pragma unroll
  for (int j = 0; j < 4; ++j) bj4[j] = *(const f32x4*)&bias[nbb + j*16];

#pragma unroll
  for (int i = 0; i < 4; ++i) {
    const int m = m0 + wr*64 + i*16 + fr;
    if constexpr (MODE == 0) {
      short* qs = (short*)out0;
      const int sec = n0 >> 7;
      const float scl = (sec == 0) ? SCALE : 1.0f;
      const int wid = m >> 8, ntok = m & 255;
      const int rowbase = sec*8388608 + (wid*8)*4096 + ntok*16 + (nbb & 15);
#pragma unroll
      for (int j = 0; j < 4; ++j) {
        const int head = ((nbb + j*16) >> 4) & 7;
        f32x4 v = acc[i][j];
        s16x4 o;
        o[0] = f2b(fmaf(v[0], scl, bj4[j].x*scl));
        o[1] = f2b(fmaf(v[1], scl, bj4[j].y*scl));
        o[2] = f2b(fmaf(v[2], scl, bj4[j].z*scl));
        o[3] = f2b(fmaf(v[3], scl, bj4[j].w*scl));
        *(s16x4*)&qs[rowbase + head*4096] = o;
      }
    } else if constexpr (MODE == 1) {
      short* y1o = (short*)out0;       // PADDED [18][34][34][4][128]
      const int wid = m >> 8, ntok = m & 255;
      const int t = ntok >> 6, gd = (ntok >> 4) & 3, gh = (ntok >> 2) & 3, gw = ntok & 3;
      const int wd = wid >> 6, wh = (wid >> 3) & 7, ww = wid & 7;
      const int sr = (((wd*4 + gd + 1)*PH + wh*4 + gh + 1)*PW + ww*4 + gw + 1)*4 + t;
      const int base = sr*CC + nbb;
#pragma unroll
      for (int j = 0; j < 4; ++j) {
        f32x4 v = acc[i][j];
        s16x4 o;
        o[0] = f2b(v[0] + bj4[j].x); o[1] = f2b(v[1] + bj4[j].y);
        o[2] = f2b(v[2] + bj4[j].z); o[3] = f2b(v[3] + bj4[j].w);
        *(s16x4*)&y1o[base + j*16] = o;
      }
    } else if constexpr (MODE == 2) {
      short* gp = (short*)out0;
      const int base = m*512 + nbb;
#pragma unroll
      for (int j = 0; j < 4; ++j) {
        f32x4 v = acc[i][j];
        s16x4 o;
        o[0] = f2b(fast_gelu(v[0] + bj4[j].x)); o[1] = f2b(fast_gelu(v[1] + bj4[j].y));
        o[2] = f2b(fast_gelu(v[2] + bj4[j].z)); o[3] = f2b(fast_gelu(v[3] + bj4[j].w));
        *(s16x4*)&gp[base + j*16] = o;
      }
    } else {
      float* outp = (float*)out0;
      const int base = m*CC + nbb;
#pragma unroll
      for (int j = 0; j < 4; ++j) {
        f32x4 v = acc[i][j];
        f16x4 rz = *(const f16x4*)&resid[base + j*16];
        f32x4 o;
        o.x = v[0] + bj4[j].x + (float)rz[0]; o.y = v[1] + bj4[j].y + (float)rz[1];
        o.z = v[2] + bj4[j].z + (float)rz[2]; o.w = v[3] + bj4[j].w + (float)rz[3];
        *(f32x4*)&outp[base + j*16] = o;
      }
    }
  }
}

// ---------------------------------------------------------------------------
// Kernel: MFMA window attention (unchanged from R2).
// ---------------------------------------------------------------------------
#define KPAD 20
#define VPAD 264
__global__ __launch_bounds__(256) void attn_mfma_kernel(
    const __hip_bfloat16* __restrict__ qb, const __hip_bfloat16* __restrict__ kb,
    const __hip_bfloat16* __restrict__ vb, __hip_bfloat16* __restrict__ ob) {
  __shared__ __align__(16) short kL[256*KPAD];
  __shared__ __align__(16) short vT[16*VPAD];
  const int bh = blockIdx.x;                // win*8 + head
  const int wid = bh >> 3, head = bh & 7;
  const int tid = threadIdx.x;
  const short* kg = (const short*)kb + (size_t)bh*4096;
  const short* vg = (const short*)vb + (size_t)bh*4096;
  const short* qg = (const short*)qb + (size_t)bh*4096;
  {
    s16x8 a0 = *(const s16x8*)&kg[tid*16];
    s16x8 a1 = *(const s16x8*)&kg[tid*16 + 8];
    *(s16x8*)&kL[tid*KPAD]     = a0;
    *(s16x8*)&kL[tid*KPAD + 8] = a1;
    s16x8 b0 = *(const s16x8*)&vg[tid*16];
    s16x8 b1 = *(const s16x8*)&vg[tid*16 + 8];
#pragma unroll
    for (int d = 0; d < 8; ++d) {
      vT[d*VPAD + tid]     = b0[d];
      vT[(d+8)*VPAD + tid] = b1[d];
    }
  }
  __syncthreads();
  const int wv = tid >> 6, lane = tid & 63;
  const int fr = lane & 15, hi = lane >> 4;
  s16x4 kfrag[16], vfrag[16];
#pragma unroll
  for (int t = 0; t < 16; ++t) {
    kfrag[t] = *(const s16x4*)&kL[(t*16 + fr)*KPAD + hi*4];
    vfrag[t] = *(const s16x4*)&vT[fr*VPAD + t*16 + hi*4];
  }
  short* obs = (short*)ob;
  for (int qt = 0; qt < 4; ++qt) {
    const int q0 = wv*64 + qt*16;
    s16x4 qfrag = *(const s16x4*)&qg[(q0 + fr)*16 + hi*4];
    f32x4 st[16];
#pragma unroll
    for (int kt = 0; kt < 16; ++kt)
      st[kt] = mfma16x16x16_bf16(kfrag[kt], qfrag, (f32x4)0.f);
    float den = 0.f;
    f32x4 oacc = (f32x4)0.f;
#pragma unroll
    for (int kt = 0; kt < 16; ++kt) {
      float e0 = __expf(st[kt][0]), e1 = __expf(st[kt][1]);
      float e2 = __expf(st[kt][2]), e3 = __expf(st[kt][3]);
      den += (e0 + e1) + (e2 + e3);
      s16x4 pa;
      pa[0] = f2b(e0); pa[1] = f2b(e1); pa[2] = f2b(e2); pa[3] = f2b(e3);
      oacc = mfma16x16x16_bf16(vfrag[kt], pa, oacc);
    }
    den += __shfl_xor(den, 16);
    den += __shfl_xor(den, 32);
    float inv = 1.f / den;
    s16x4 ov;
    ov[0] = f2b(oacc[0]*inv); ov[1] = f2b(oacc[1]*inv);
    ov[2] = f2b(oacc[2]*inv); ov[3] = f2b(oacc[3]*inv);
    *(s16x4*)&obs[((size_t)wid*256 + q0 + fr)*CC + head*16 + hi*4] = ov;
  }
}

// ---------------------------------------------------------------------------
// Kernel: FUSED conv3x3x3 (padded bf16 in, NO guards) + exln + norm2.
// R8's proven structure: thread = (site, c8-group), 4 independent t-chains.
// ---------------------------------------------------------------------------
__global__ __launch_bounds__(256) void conv_ln_kernel(
    const __hip_bfloat16* __restrict__ y1p, const float* __restrict__ wT,
    const float* __restrict__ cb,
    const float* __restrict__ exg, const float* __restrict__ exb,
    const float* __restrict__ n2g, const float* __restrict__ n2b,
    _Float16* __restrict__ yb, __hip_bfloat16* __restrict__ h2) {
  const int tid = threadIdx.x;
  const int sp = blockIdx.x*16 + (tid >> 4);     // spatial site 0..16383
  const int cbase = (tid & 15) * 8;              // 8-channel group
  const int w = sp & 31, h = (sp >> 5) & 31, d = sp >> 10;
  const int psite = ((d+1)*PH + (h+1))*PW + (w+1);
  const short* base = (const short*)y1p + (size_t)psite*512 + cbase;

  float acc[4][8];
  {
    f32x4 cb0 = *(const f32x4*)&cb[cbase];
    f32x4 cb1 = *(const f32x4*)&cb[cbase + 4];
#pragma unroll
    for (int t = 0; t < 4; ++t) {
      acc[t][0]=cb0.x; acc[t][1]=cb0.y; acc[t][2]=cb0.z; acc[t][3]=cb0.w;
      acc[t][4]=cb1.x; acc[t][5]=cb1.y; acc[t][6]=cb1.z; acc[t][7]=cb1.w;
    }
  }

#pragma unroll
  for (int dd = -1; dd <= 1; ++dd)
#pragma unroll
    for (int dh = -1; dh <= 1; ++dh)
#pragma unroll
      for (int dw = -1; dw <= 1; ++dw) {
        const int tap = ((dd+1)*3 + (dh+1))*3 + (dw+1);
        const int toff = ((dd*PH + dh)*PW + dw)*512;
        f32x4 w0 = *(const f32x4*)&wT[tap*CC + cbase];
        f32x4 w1 = *(const f32x4*)&wT[tap*CC + cbase + 4];
#pragma unroll
        for (int t = 0; t < 4; ++t) {
          s16x8 v = *(const s16x8*)(base + toff + t*CC);
          acc[t][0] = fmaf(b2f(v[0]), w0.x, acc[t][0]);
          acc[t][1] = fmaf(b2f(v[1]), w0.y, acc[t][1]);
          acc[t][2] = fmaf(b2f(v[2]), w0.z, acc[t][2]);
          acc[t][3] = fmaf(b2f(v[3]), w0.w, acc[t][3]);
          acc[t][4] = fmaf(b2f(v[4]), w1.x, acc[t][4]);
          acc[t][5] = fmaf(b2f(v[5]), w1.y, acc[t][5]);
          acc[t][6] = fmaf(b2f(v[6]), w1.z, acc[t][6]);
          acc[t][7] = fmaf(b2f(v[7]), w1.w, acc[t][7]);
        }
      }

  f32x4 eg0 = *(const f32x4*)&exg[cbase], eg1 = *(const f32x4*)&exg[cbase+4];
  f32x4 eb0 = *(const f32x4*)&exb[cbase], eb1 = *(const f32x4*)&exb[cbase+4];
  f32x4 ng0 = *(const f32x4*)&n2g[cbase], ng1 = *(const f32x4*)&n2g[cbase+4];
  f32x4 nb0 = *(const f32x4*)&n2b[cbase], nb1 = *(const f32x4*)&n2b[cbase+4];
  float eg[8] = {eg0.x,eg0.y,eg0.z,eg0.w,eg1.x,eg1.y,eg1.z,eg1.w};
  float eb[8] = {eb0.x,eb0.y,eb0.z,eb0.w,eb1.x,eb1.y,eb1.z,eb1.w};
  float ng[8] = {ng0.x,ng0.y,ng0.z,ng0.w,ng1.x,ng1.y,ng1.z,ng1.w};
  float nb[8] = {nb0.x,nb0.y,nb0.z,nb0.w,nb1.x,nb1.y,nb1.z,nb1.w};

#pragma unroll
  for (int t = 0; t < 4; ++t) {
    float s = 0.f, sq = 0.f;
#pragma unroll
    for (int c = 0; c < 8; ++c) { s += acc[t][c]; sq = fmaf(acc[t][c], acc[t][c], sq); }
#pragma unroll
    for (int m = 1; m <= 8; m <<= 1) { s += __shfl_xor(s, m); sq += __shfl_xor(sq, m); }
    float mean = s * (1.f/128.f);
    float var  = sq * (1.f/128.f) - mean*mean;
    float rstd = rsqrtf(var + LNEPS);
    float y[8];
    f16x8 yo;
#pragma unroll
    for (int c = 0; c < 8; ++c) {
      y[c] = (acc[t][c] - mean)*rstd*eg[c] + eb[c];
      yo[c] = (_Float16)y[c];
    }
    *(f16x8*)&yb[(size_t)(sp*4 + t)*CC + cbase] = yo;
    float s2 = 0.f, sq2 = 0.f;
#pragma unroll
    for (int c = 0; c < 8; ++c) { s2 += y[c]; sq2 = fmaf(y[c], y[c], sq2); }
#pragma unroll
    for (int m = 1; m <= 8; m <<= 1) { s2 += __shfl_xor(s2, m); sq2 += __shfl_xor(sq2, m); }
    float mean2 = s2 * (1.f/128.f);
    float var2  = sq2 * (1.f/128.f) - mean2*mean2;
    float rstd2 = rsqrtf(var2 + LNEPS);
    s16x8 ho;
#pragma unroll
    for (int c = 0; c < 8; ++c)
      ho[c] = f2b((y[c] - mean2)*rstd2*ng[c] + nb[c]);
    *(s16x8*)&((short*)h2)[(size_t)(sp*4 + t)*CC + cbase] = ho;
  }
}

// ---------------------------------------------------------------------------
// Launch
// ---------------------------------------------------------------------------
extern "C" void kernel_launch(void* const* d_in, const int* in_sizes, int n_in,
                              void* d_out, int out_size, void* d_ws, size_t ws_size,
                              hipStream_t stream) {
  const float* x      = (const float*)d_in[0];
  const float* n1g    = (const float*)d_in[1];
  const float* n1b    = (const float*)d_in[2];
  const float* pos    = (const float*)d_in[3];
  const float* te     = (const float*)d_in[4];
  const float* qkv_w  = (const float*)d_in[5];
  const float* qkv_b  = (const float*)d_in[6];
  const float* proj_w = (const float*)d_in[7];
  const float* proj_b = (const float*)d_in[8];
  const float* conv_w = (const float*)d_in[9];
  const float* conv_b = (const float*)d_in[10];
  const float* exg    = (const float*)d_in[11];
  const float* exb    = (const float*)d_in[12];
  const float* n2g    = (const float*)d_in[13];
  const float* n2b    = (const float*)d_in[14];
  const float* fc1_w  = (const float*)d_in[15];
  const float* fc1_b  = (const float*)d_in[16];
  const float* fc2_w  = (const float*)d_in[17];
  const float* fc2_b  = (const float*)d_in[18];

  char* wsb = (char*)d_ws;
  __hip_bfloat16* wq  = (__hip_bfloat16*)(wsb);             // 384x128
  __hip_bfloat16* wp  = (__hip_bfloat16*)(wsb + 98304);     // 128x128
  __hip_bfloat16* w1  = (__hip_bfloat16*)(wsb + 131072);    // 512x128
  __hip_bfloat16* w2  = (__hip_bfloat16*)(wsb + 262144);    // 128x512
  float*          cwT = (float*)(wsb + 393216);             // 27x128

  const size_t A_OFF = (size_t)1 << 20;                     // 16 MiB region
  const size_t B_OFF = A_OFF + ((size_t)16 << 20);          // 48 MiB region
  const size_t C_OFF = B_OFF + ((size_t)48 << 20);          // 64 MiB region

  __hip_bfloat16* hbuf = (__hip_bfloat16*)(wsb + A_OFF);    // LN1 out
  __hip_bfloat16* obuf = (__hip_bfloat16*)(wsb + A_OFF);    // attn out (reuses A)
  __hip_bfloat16* h2in = (__hip_bfloat16*)(wsb + A_OFF);    // MLP in (reuses A)
  __hip_bfloat16* qkvb = (__hip_bfloat16*)(wsb + B_OFF);    // q|k|v, 16MiB each
  __hip_bfloat16* qb   = qkvb;
  __hip_bfloat16* kb   = qkvb + 8388608;
  __hip_bfloat16* vb   = qkvb + 16777216;
  __hip_bfloat16* y1p  = (__hip_bfloat16*)(wsb + B_OFF);    // padded proj out (20.3 MiB, over q+k)
  _Float16* yb = (_Float16*)(wsb + B_OFF + ((size_t)24 << 20)); // fp16 y (16 MiB)
  __hip_bfloat16* gbuf = (__hip_bfloat16*)(wsb + C_OFF);    // GELU out (64 MiB)

  prep_kernel<<<782, 256, 0, stream>>>(qkv_w, proj_w, fc1_w, fc2_w, conv_w,
                                       wq, wp, w1, w2, cwT);
  ln1_pe_kernel<<<TOKS/4, 256, 0, stream>>>(x, n1g, n1b, pos, te, hbuf);
  gemm_kernel<0, 128><<<dim3(TOKS/128, 3), 256, 0, stream>>>(
      (const short*)hbuf, (const short*)wq, qkv_b, (void*)qkvb, nullptr);
  attn_mfma_kernel<<<NWIN*8, 256, 0, stream>>>(qb, kb, vb, obuf);
  border_zero_kernel<<<(PSITES*64 + 255)/256, 256, 0, stream>>>((short*)y1p);
  gemm_kernel<1, 128><<<dim3(TOKS/128, 1), 256, 0, stream>>>(
      (const short*)obuf, (const short*)wp, proj_b, (void*)y1p, nullptr);
  conv_ln_kernel<<<16384/16, 256, 0, stream>>>(y1p, cwT, conv_b,
      exg, exb, n2g, n2b, yb, h2in);
  gemm_kernel<2, 128><<<dim3(TOKS/128, 4), 256, 0, stream>>>(
      (const short*)h2in, (const short*)w1, fc1_b, (void*)gbuf, nullptr);
  gemm_kernel<3, 512><<<dim3(TOKS/128, 1), 256, 0, stream>>>(
      (const short*)gbuf, (const short*)w2, fc2_b, (void*)d_out, yb);
}